// Round 16
// baseline (269.388 us; speedup 1.0000x reference)
//
#include <hip/hip_runtime.h>
#include <stdint.h>

// ---------------------------------------------------------------------------
// WindowedSelfAttentionLayer: B=2 S=2048 D=1024 H=16 HID=4096 WIN=256
//  - gemm256p: 256x256-tile, 8-wave, BK=32, 64KB LDS -> 2 blocks/CU
//    co-residency (m114 overlap absorbs the 2-phase stage/barrier stall).
//    Sync skeleton IDENTICAL to the R7/R12-proven 2-phase pipeline
//    (STAGE next parity -> counted vmcnt -> BAR -> COMPUTE -> BAR).
//    EPI1 = QKV (Q|K + V-transposed), EPI2 = fused SwiGLU (bf16 u-exchange),
//    EPI3 = Wd split-K bf16 partial.
//  - gemm_bf16t: m97-style 128x128 for Wo.
//  - attn_mfma: MFMA windowed attention, 80KB LDS, 2 blocks/CU.
//  - tr_cast_multi: z-fused weight transposes.
// ---------------------------------------------------------------------------

typedef __bf16 bf16;
typedef bf16  bf16x8 __attribute__((ext_vector_type(8)));
typedef bf16  bf16x4v __attribute__((ext_vector_type(4)));
typedef float f32x4  __attribute__((ext_vector_type(4)));

#define S_LEN 2048

#define GLDS16(gp, lp)                                                          \
  __builtin_amdgcn_global_load_lds(                                            \
      (__attribute__((address_space(1))) void*)(gp),                            \
      (__attribute__((address_space(3))) void*)(lp), 16, 0, 0)

// ---------------------------------------------------------------------------
__global__ __launch_bounds__(256) void ln_bf16(const float* __restrict__ x,
                                               const float* __restrict__ w,
                                               const float* __restrict__ bb,
                                               bf16* __restrict__ out) {
  const int row = blockIdx.x, tid = threadIdx.x;
  const int wid = tid >> 6, lane = tid & 63;
  const float4 v = ((const float4*)(x + (size_t)row * 1024))[tid];
  float s = v.x + v.y + v.z + v.w;
  float q = v.x * v.x + v.y * v.y + v.z * v.z + v.w * v.w;
#pragma unroll
  for (int off = 32; off > 0; off >>= 1) {
    s += __shfl_xor(s, off);
    q += __shfl_xor(q, off);
  }
  __shared__ float rs_[4], rq_[4];
  if (lane == 0) { rs_[wid] = s; rq_[wid] = q; }
  __syncthreads();
  s = rs_[0] + rs_[1] + rs_[2] + rs_[3];
  q = rq_[0] + rq_[1] + rq_[2] + rq_[3];
  const float mean = s * (1.f / 1024.f);
  const float var  = q * (1.f / 1024.f) - mean * mean;
  const float rstd = rsqrtf(var + 1e-5f);
  const float4 wv = ((const float4*)w)[tid];
  const float4 bv = ((const float4*)bb)[tid];
  bf16x4v o;
  o[0] = (bf16)((v.x - mean) * rstd * wv.x + bv.x);
  o[1] = (bf16)((v.y - mean) * rstd * wv.y + bv.y);
  o[2] = (bf16)((v.z - mean) * rstd * wv.z + bv.z);
  o[3] = (bf16)((v.w - mean) * rstd * wv.w + bv.w);
  ((bf16x4v*)(out + (size_t)row * 1024))[tid] = o;
}

// ---------------------------------------------------------------------------
__global__ __launch_bounds__(256) void tr_cast_multi(
    const float* __restrict__ a, const float* __restrict__ b,
    const float* __restrict__ c, bf16* __restrict__ out, int R, int C) {
  const float* in = (blockIdx.z == 0) ? a : (blockIdx.z == 1 ? b : c);
  bf16* o = out + (size_t)blockIdx.z * R * C;
  __shared__ float t[32][33];
  const int tx = threadIdx.x, ty = threadIdx.y;
  const int r0 = blockIdx.y * 32, c0 = blockIdx.x * 32;
#pragma unroll
  for (int i = 0; i < 4; ++i)
    t[ty + 8 * i][tx] = in[(size_t)(r0 + ty + 8 * i) * C + c0 + tx];
  __syncthreads();
#pragma unroll
  for (int i = 0; i < 4; ++i)
    o[(size_t)(c0 + ty + 8 * i) * R + r0 + tx] = (bf16)t[tx][ty + 8 * i];
}

__global__ void concat3(const float* __restrict__ a, const float* __restrict__ b,
                        const float* __restrict__ c, float* __restrict__ o) {
  int i = blockIdx.x * 256 + threadIdx.x;
  if (i < 1024) o[i] = a[i];
  else if (i < 2048) o[i] = b[i - 1024];
  else if (i < 3072) o[i] = c[i - 2048];
}

// ---------------------------------------------------------------------------
// BK=32 256x256 GEMM, K=1024/slice (32 K-tiles), 512 thr = 8 waves (2Mx4N).
// LDS 64KB: A[parity][256 rows][32 bf16] (16KB each) + B same -> 2 blk/CU.
// Per K-tile: STAGE next tile into other parity (4 gloads: 2A+2B) ->
// vmcnt(4)+bar -> 12 ds_read_b128 + 32 MFMA -> bar.  Linear layout: at 64B
// rows, lanes (fr,fq) naturally hit 8 slots x 8 lanes = b128 bank floor.
// EPI1 = QKV, EPI2 = fused SwiGLU (u exchanged via bf16 LDS), EPI3 = splitK.
// ---------------------------------------------------------------------------
template <int EPI>
__global__ __launch_bounds__(512, 2) void gemm256p(
    const bf16* __restrict__ A, const bf16* __restrict__ BT,
    const bf16* __restrict__ BT2, const float* __restrict__ bias,
    const float* __restrict__ bias2, bf16* __restrict__ outp,
    bf16* __restrict__ vout, bf16* __restrict__ pout,
    int Astr, int Bstr) {
  __shared__ char smem[65536];
  char* A0 = smem;
  char* A1 = smem + 16384;
  char* B0 = smem + 32768;
  char* B1 = smem + 49152;

  const int tid = threadIdx.x, wid = tid >> 6, lane = tid & 63;
  const int fr = lane & 15, fq = lane >> 4;
  const int wr = wid >> 2, wc = wid & 3;
  const int wm = wr * 128, wn = wc * 64;

  int wg = blockIdx.x;
  {
    const int nwg = gridDim.x;
    int qq = nwg >> 3, rr = nwg & 7, xc = wg & 7, ix = wg >> 3;
    wg = (xc < rr ? xc * (qq + 1) : rr * (qq + 1) + (xc - rr) * qq) + ix;
  }
  int mtile, ntile, ks = 0;
  if constexpr (EPI == 3) { mtile = wg & 15; ntile = (wg >> 4) & 3; ks = wg >> 6; }
  else                    { mtile = wg & 15; ntile = wg >> 4; }
  const int m0 = mtile * 256;
  const int nbase = (EPI == 2) ? ntile * 128 : ntile * 256;
  const size_t kbase = (size_t)ks << 10;

  // staging: chunk = 16 rows x 64B; lane -> (row = lane>>2, seg = lane&3)
  const int srow = lane >> 2;
  const int sseg = (lane & 3) * 8;
  const bf16* pA = A + (size_t)(m0 + wid * 32 + srow) * Astr + kbase + sseg;
  const bf16* pB;
  if constexpr (EPI == 2) {
    const bf16* srcB = (wid < 4) ? BT : BT2;
    pB = srcB + (size_t)(nbase + (wid & 3) * 32 + srow) * Bstr + kbase + sseg;
  } else {
    pB = BT + (size_t)(nbase + wid * 32 + srow) * Bstr + kbase + sseg;
  }
  const size_t rA16 = (size_t)16 * Astr;
  const size_t rB16 = (size_t)16 * Bstr;
  const int cOff = wid * 2048;  // 2KB per wave per matrix

  auto STAGE = [&](char* aD, char* bD, int kt) {
    const size_t ko = (size_t)kt * 32;
    GLDS16(pA + ko,        aD + cOff);
    GLDS16(pA + rA16 + ko, aD + cOff + 1024);
    GLDS16(pB + ko,        bD + cOff);
    GLDS16(pB + rB16 + ko, bD + cOff + 1024);
  };

  const int aOff = (wm + fr) * 64 + fq * 16;  // bytes; + q*1024
  const int bOff = (wn + fr) * 64 + fq * 16;  // bytes; + nj*1024

  f32x4 acc[8][4];
#pragma unroll
  for (int i = 0; i < 8; ++i)
#pragma unroll
    for (int j = 0; j < 4; ++j) acc[i][j] = f32x4{0.f, 0.f, 0.f, 0.f};

  auto COMPUTE = [&](const char* aB, const char* bB) {
    bf16x8 bv[4], av[4];
#pragma unroll
    for (int nj = 0; nj < 4; ++nj)
      bv[nj] = *(const bf16x8*)(bB + bOff + nj * 1024);
#pragma unroll
    for (int q = 0; q < 4; ++q)
      av[q] = *(const bf16x8*)(aB + aOff + q * 1024);
    __builtin_amdgcn_s_setprio(1);
#pragma unroll
    for (int q = 0; q < 4; ++q)
#pragma unroll
      for (int nj = 0; nj < 4; ++nj)
        acc[q][nj] = __builtin_amdgcn_mfma_f32_16x16x32_bf16(
            av[q], bv[nj], acc[q][nj], 0, 0, 0);
    __builtin_amdgcn_s_setprio(0);
#pragma unroll
    for (int q = 0; q < 4; ++q)
      av[q] = *(const bf16x8*)(aB + aOff + 4096 + q * 1024);
    __builtin_amdgcn_s_setprio(1);
#pragma unroll
    for (int q = 0; q < 4; ++q)
#pragma unroll
      for (int nj = 0; nj < 4; ++nj)
        acc[4 + q][nj] = __builtin_amdgcn_mfma_f32_16x16x32_bf16(
            av[q], bv[nj], acc[4 + q][nj], 0, 0, 0);
    __builtin_amdgcn_s_setprio(0);
  };

#define VM4()  asm volatile("s_waitcnt vmcnt(4)" ::: "memory")
#define VM0()  asm volatile("s_waitcnt vmcnt(0)" ::: "memory")
#define BAR()  __builtin_amdgcn_s_barrier()

  STAGE(A0, B0, 0);
#pragma unroll 1
  for (int t2 = 0; t2 < 15; ++t2) {
    STAGE(A1, B1, 2 * t2 + 1);  VM4();  BAR();
    COMPUTE(A0, B0);            BAR();
    STAGE(A0, B0, 2 * t2 + 2);  VM4();  BAR();
    COMPUTE(A1, B1);            BAR();
  }
  STAGE(A1, B1, 31);  VM4();  BAR();
  COMPUTE(A0, B0);    BAR();
  VM0();  BAR();
  COMPUTE(A1, B1);    BAR();

  if constexpr (EPI == 1) {
    if (nbase < 2048) {  // Q|K -> [4096][2048]
#pragma unroll
      for (int mi = 0; mi < 8; ++mi)
#pragma unroll
        for (int nj = 0; nj < 4; ++nj) {
          const int grow = m0 + wm + mi * 16 + fq * 4;
          const int gcol = nbase + wn + nj * 16 + fr;
          const float bc = bias[gcol];
#pragma unroll
          for (int r = 0; r < 4; ++r)
            outp[(size_t)(grow + r) * 2048 + gcol] = (bf16)(acc[mi][nj][r] + bc);
        }
    } else {  // V -> vT[(b*1024+d)][t]
#pragma unroll
      for (int mi = 0; mi < 8; ++mi)
#pragma unroll
        for (int nj = 0; nj < 4; ++nj) {
          const int grow = m0 + wm + mi * 16 + fq * 4;
          const int gcol = nbase + wn + nj * 16 + fr;
          const float bc = bias[gcol];
          bf16x4v pk;
#pragma unroll
          for (int r = 0; r < 4; ++r) pk[r] = (bf16)(acc[mi][nj][r] + bc);
          *(bf16x4v*)(vout + ((size_t)((grow >> 11) * 1024 + (gcol - 2048))) * 2048 +
                      (grow & 2047)) = pk;
        }
    }
  } else if constexpr (EPI == 2) {  // fused silu(g)*u, u exchanged as bf16
    bf16* uls = (bf16*)smem;        // [256][128] bf16 = 64KB
    if (wn >= 128) {
#pragma unroll
      for (int mi = 0; mi < 8; ++mi)
#pragma unroll
        for (int nj = 0; nj < 4; ++nj) {
          const int rowL = wm + mi * 16 + fq * 4;
          const int cu = wn - 128 + nj * 16 + fr;
          const float bc = bias2[nbase + cu];
#pragma unroll
          for (int r = 0; r < 4; ++r)
            uls[(rowL + r) * 128 + cu] = (bf16)(acc[mi][nj][r] + bc);
        }
    }
    __syncthreads();
    if (wn < 128) {
#pragma unroll
      for (int mi = 0; mi < 8; ++mi)
#pragma unroll
        for (int nj = 0; nj < 4; ++nj) {
          const int rowL = wm + mi * 16 + fq * 4;
          const int cg = wn + nj * 16 + fr;
          const float bc = bias[nbase + cg];
#pragma unroll
          for (int r = 0; r < 4; ++r) {
            const float g = acc[mi][nj][r] + bc;
            const float u = (float)uls[(rowL + r) * 128 + cg];
            outp[(size_t)(m0 + rowL + r) * 4096 + nbase + cg] =
                (bf16)(g * u / (1.f + __expf(-g)));
          }
        }
    }
  } else {  // EPI 3: bf16 partial [4096][1024] for split-K slice ks
    bf16* po = pout + ((size_t)ks << 22);
#pragma unroll
    for (int mi = 0; mi < 8; ++mi)
#pragma unroll
      for (int nj = 0; nj < 4; ++nj) {
        const int grow = m0 + wm + mi * 16 + fq * 4;
        const int gcol = nbase + wn + nj * 16 + fr;
#pragma unroll
        for (int r = 0; r < 4; ++r)
          po[(size_t)(grow + r) * 1024 + gcol] = (bf16)acc[mi][nj][r];
      }
  }
#undef VM4
#undef VM0
#undef BAR
}

// out = x1 + bd + sum_{k<4} parts[k]
__global__ __launch_bounds__(256) void reduce_wd(
    const float* __restrict__ x1, const float* __restrict__ bd,
    const bf16* __restrict__ parts, float* __restrict__ out) {
  const size_t i = (size_t)blockIdx.x * 256 + threadIdx.x;
  const float4 a  = ((const float4*)x1)[i];
  const float4 bv = ((const float4*)bd)[i & 255];
  float s0 = a.x + bv.x, s1 = a.y + bv.y, s2 = a.z + bv.z, s3 = a.w + bv.w;
#pragma unroll
  for (int k = 0; k < 4; ++k) {
    const bf16x4v p = ((const bf16x4v*)(parts + ((size_t)k << 22)))[i];
    s0 += (float)p[0]; s1 += (float)p[1]; s2 += (float)p[2]; s3 += (float)p[3];
  }
  ((float4*)out)[i] = make_float4(s0, s1, s2, s3);
}

// ---------------------------------------------------------------------------
// m97-style 128x128 GEMM.  EPI 1: fp32 out + residual (Wo).
// ---------------------------------------------------------------------------
template <int EPI>
__global__ __launch_bounds__(256) void gemm_bf16t(
    const bf16* __restrict__ A, const bf16* __restrict__ BT,
    const float* __restrict__ bias, const float* __restrict__ res,
    void* __restrict__ Cout, int M, int N, int K) {
  __shared__ bf16 sA[128 * 64];
  __shared__ bf16 sB[128 * 64];
  const int tid = threadIdx.x;
  const int wid = tid >> 6, lane = tid & 63;
  const int m0 = blockIdx.y * 128, n0 = blockIdx.x * 128;
  const int wm = (wid >> 1) * 64, wn = (wid & 1) * 64;
  const int lrow = lane >> 3, lseg = (lane & 7) * 8;
  const int fr = lane & 15, fq = lane >> 4;

  f32x4 acc[4][4];
#pragma unroll
  for (int i = 0; i < 4; ++i)
#pragma unroll
    for (int j = 0; j < 4; ++j) acc[i][j] = f32x4{0.f, 0.f, 0.f, 0.f};

  for (int k0 = 0; k0 < K; k0 += 64) {
#pragma unroll
    for (int it = 0; it < 4; ++it) {
      const int c = wid * 4 + it;
      const int row = c * 8 + lrow;
      GLDS16(A  + (size_t)(m0 + row) * K + k0 + lseg, sA + c * 512);
      GLDS16(BT + (size_t)(n0 + row) * K + k0 + lseg, sB + c * 512);
    }
    __syncthreads();
#pragma unroll
    for (int kk = 0; kk < 64; kk += 32) {
      bf16x8 af[4], bfv[4];
#pragma unroll
      for (int i = 0; i < 4; ++i)
        af[i] = *(const bf16x8*)(sA + (wm + i * 16 + fr) * 64 + kk + 8 * fq);
#pragma unroll
      for (int j = 0; j < 4; ++j)
        bfv[j] = *(const bf16x8*)(sB + (wn + j * 16 + fr) * 64 + kk + 8 * fq);
#pragma unroll
      for (int i = 0; i < 4; ++i)
#pragma unroll
        for (int j = 0; j < 4; ++j)
          acc[i][j] = __builtin_amdgcn_mfma_f32_16x16x32_bf16(af[i], bfv[j],
                                                              acc[i][j], 0, 0, 0);
    }
    __syncthreads();
  }

#pragma unroll
  for (int i = 0; i < 4; ++i) {
    const int grow = m0 + wm + i * 16 + fq * 4;
#pragma unroll
    for (int j = 0; j < 4; ++j) {
      const int gcol = n0 + wn + j * 16 + fr;
      const float bc = bias[gcol];
#pragma unroll
      for (int r = 0; r < 4; ++r) {
        const size_t idx = (size_t)(grow + r) * N + gcol;
        const float v = acc[i][j][r] + bc;
        if constexpr (EPI == 1) {
          ((float*)Cout)[idx] = v + res[idx];
        } else {
          ((bf16*)Cout)[idx] = (bf16)v;
        }
      }
    }
  }
}

// ---------------------------------------------------------------------------
// MFMA windowed attention, 80KB LDS, 2 blocks/CU (R12/R15-measured).
// ---------------------------------------------------------------------------
__global__ __launch_bounds__(256) void attn_mfma(const bf16* __restrict__ qk,
                                                 const bf16* __restrict__ vT,
                                                 bf16* __restrict__ ctx) {
  __shared__ bf16 sK[320 * 64];
  __shared__ bf16 sP[64 * 320];
  const int bh = blockIdx.x;
  const int b = bh >> 4, h = bh & 15;
  const int qs0 = blockIdx.y * 64;
  const int t0 = qs0 - 128;
  const int tS = t0 < 0 ? 0 : (t0 > S_LEN - 320 ? S_LEN - 320 : t0);
  const int tid = threadIdx.x, wid = tid >> 6, lane = tid & 63;
  const size_t bbase = (size_t)b * S_LEN;

  {
    const int srow8 = lane >> 3;
    const int gseg = (lane & 7) ^ srow8;
#pragma unroll
    for (int i = 0; i < 10; ++i) {
      const int c = wid * 10 + i;
      const bf16* gp = qk + (bbase + tS + 8 * c + srow8) * 2048 + 1024 +
                       h * 64 + gseg * 8;
      GLDS16(gp, (char*)sK + c * 1024);
    }
  }
  __syncthreads();

  const int fr = lane & 15, fq = lane >> 4;
  const int fx = fr & 7;

  const bf16* qrowp = qk + (bbase + qs0 + wid * 16 + fr) * 2048 + h * 64;
  const bf16x8 aq0 = *(const bf16x8*)(qrowp + 8 * fq);
  const bf16x8 aq1 = *(const bf16x8*)(qrowp + 32 + 8 * fq);

  f32x4 s[20];
#pragma unroll
  for (int j = 0; j < 20; ++j) s[j] = f32x4{0.f, 0.f, 0.f, 0.f};
#pragma unroll
  for (int j = 0; j < 20; ++j) {
    const bf16* kb = sK + (j * 16 + fr) * 64;
    const bf16x8 bk0 = *(const bf16x8*)(kb + ((fq ^ fx) << 3));
    const bf16x8 bk1 = *(const bf16x8*)(kb + (((4 + fq) ^ fx) << 3));
    s[j] = __builtin_amdgcn_mfma_f32_16x16x32_bf16(aq0, bk0, s[j], 0, 0, 0);
    s[j] = __builtin_amdgcn_mfma_f32_16x16x32_bf16(aq1, bk1, s[j], 0, 0, 0);
  }

#pragma unroll
  for (int r = 0; r < 4; ++r) {
    const int rowq = wid * 16 + fq * 4 + r;
    const int q_g = qs0 + rowq;
    float m = -1e30f;
#pragma unroll
    for (int j = 0; j < 20; ++j) {
      const int t_g = tS + j * 16 + fr;
      const bool ok = (unsigned)(q_g - t_g + 128) <= 256u;
      const float val = ok ? s[j][r] * 0.125f : -1e30f;
      s[j][r] = val;
      m = fmaxf(m, val);
    }
#pragma unroll
    for (int off = 1; off < 16; off <<= 1) m = fmaxf(m, __shfl_xor(m, off));
    float sm = 0.f;
#pragma unroll
    for (int j = 0; j < 20; ++j) {
      const float p = __expf(s[j][r] - m);
      s[j][r] = p;
      sm += p;
    }
#pragma unroll
    for (int off = 1; off < 16; off <<= 1) sm += __shfl_xor(sm, off);
    const float inv = 1.f / sm;
    const int rk = rowq & 7;
#pragma unroll
    for (int j = 0; j < 20; ++j) {
      const int seg = 2 * j + (fr >> 3);
      sP[rowq * 320 + (((seg ^ rk) << 3) | fx)] = (bf16)(s[j][r] * inv);
    }
  }
  __syncthreads();

  f32x4 o[4];
#pragma unroll
  for (int j = 0; j < 4; ++j) o[j] = f32x4{0.f, 0.f, 0.f, 0.f};
  const bf16* vbase = vT + ((size_t)bh * 64) * 2048 + tS;
  const bf16* pbase = sP + (wid * 16 + fr) * 320;
#pragma unroll
  for (int ks = 0; ks < 10; ++ks) {
    const int kk = ks * 32;
    const bf16x8 pa = *(const bf16x8*)(pbase + (((4 * ks + fq) ^ fx) << 3));
#pragma unroll
    for (int j = 0; j < 4; ++j) {
      const bf16x8 vb = *(const bf16x8*)(vbase + (size_t)(j * 16 + fr) * 2048 +
                                         kk + 8 * fq);
      o[j] = __builtin_amdgcn_mfma_f32_16x16x32_bf16(pa, vb, o[j], 0, 0, 0);
    }
  }
#pragma unroll
  for (int j = 0; j < 4; ++j)
#pragma unroll
    for (int r = 0; r < 4; ++r) {
      const int q = qs0 + wid * 16 + fq * 4 + r;
      ctx[(bbase + q) * 1024 + h * 64 + j * 16 + fr] = (bf16)o[j][r];
    }
}

// ---------------------------------------------------------------------------
extern "C" void kernel_launch(void* const* d_in, const int* in_sizes, int n_in,
                              void* d_out, int out_size, void* d_ws, size_t ws_size,
                              hipStream_t stream) {
  const float* x    = (const float*)d_in[0];
  const float* ln1w = (const float*)d_in[2];
  const float* ln1b = (const float*)d_in[3];
  const float* Wq   = (const float*)d_in[4];
  const float* bq   = (const float*)d_in[5];
  const float* Wk   = (const float*)d_in[6];
  const float* bk   = (const float*)d_in[7];
  const float* Wv   = (const float*)d_in[8];
  const float* bv   = (const float*)d_in[9];
  const float* Wo   = (const float*)d_in[10];
  const float* bo   = (const float*)d_in[11];
  const float* ln2w = (const float*)d_in[12];
  const float* ln2b = (const float*)d_in[13];
  const float* Wg   = (const float*)d_in[14];
  const float* bg   = (const float*)d_in[15];
  const float* Wu   = (const float*)d_in[16];
  const float* bu   = (const float*)d_in[17];
  const float* Wd   = (const float*)d_in[18];
  const float* bd   = (const float*)d_in[19];

  char* ws = (char*)d_ws;
  size_t off = 0;
  auto take = [&](size_t bytes) {
    char* p = ws + off;
    off += (bytes + 255) & ~(size_t)255;
    return p;
  };
  bf16*  wqkvT = (bf16*)take((size_t)3072 * 1024 * 2);
  bf16*  woT   = (bf16*)take((size_t)1024 * 1024 * 2);
  bf16*  wgT   = (bf16*)take((size_t)4096 * 1024 * 2);
  bf16*  wuT   = (bf16*)take((size_t)4096 * 1024 * 2);
  bf16*  wdT   = (bf16*)take((size_t)1024 * 4096 * 2);
  float* bqkv  = (float*)take((size_t)3072 * 4);
  bf16*  h     = (bf16*)take((size_t)4096 * 1024 * 2);   // 8MB  } h..vT: 40MB
  bf16*  qk    = (bf16*)take((size_t)4096 * 2048 * 2);   // 16MB } dead by Wd;
  bf16*  ctx   = (bf16*)take((size_t)4096 * 1024 * 2);   // 8MB  } partials=32MB
  bf16*  vT    = (bf16*)take((size_t)2048 * 2048 * 2);   // 8MB  }
  float* x1    = (float*)take((size_t)4096 * 1024 * 4);
  bf16*  h2    = (bf16*)take((size_t)4096 * 1024 * 2);
  bf16*  gated = (bf16*)take((size_t)4096 * 4096 * 2);
  bf16*  parts = h;
  (void)ws_size; (void)in_sizes; (void)n_in; (void)out_size;

  const dim3 tb(32, 8);
  tr_cast_multi<<<dim3(32, 32, 3), tb, 0, stream>>>(Wq, Wk, Wv, wqkvT, 1024, 1024);
  tr_cast_multi<<<dim3(128, 32, 2), tb, 0, stream>>>(Wg, Wu, nullptr, wgT, 1024, 4096);
  tr_cast_multi<<<dim3(32, 128, 1), tb, 0, stream>>>(Wd, nullptr, nullptr, wdT, 4096, 1024);
  tr_cast_multi<<<dim3(32, 32, 1), tb, 0, stream>>>(Wo, nullptr, nullptr, woT, 1024, 1024);
  concat3<<<12, 256, 0, stream>>>(bq, bk, bv, bqkv);

  // LN1 -> h
  ln_bf16<<<4096, 256, 0, stream>>>(x, ln1w, ln1b, h);
  // QKV on gemm256p (grid 16m x 12n = 192): Q|K -> qk, V -> vT
  gemm256p<1><<<192, 512, 0, stream>>>(h, wqkvT, nullptr, bqkv, nullptr,
                                       qk, vT, nullptr, 1024, 1024);
  // windowed attention -> ctx bf16
  attn_mfma<<<dim3(32, 32), 256, 0, stream>>>(qk, vT, ctx);
  // x1 = x + ctx @ Wo + bo
  gemm_bf16t<1><<<dim3(8, 32), 256, 0, stream>>>(ctx, woT, bo, x,
                                                 x1, 4096, 1024, 1024);
  // LN2 -> h2
  ln_bf16<<<4096, 256, 0, stream>>>(x1, ln2w, ln2b, h2);
  // gated = silu(h2@Wg+bg) * (h2@Wu+bu)
  gemm256p<2><<<512, 512, 0, stream>>>(h2, wgT, wuT, bg, bu, gated,
                                       nullptr, nullptr, 1024, 1024);
  // Wd split-K=4: bf16 partials, then out = x1 + bd + sum(parts)
  gemm256p<3><<<256, 512, 0, stream>>>(gated, wdT, nullptr, nullptr, nullptr,
                                       nullptr, nullptr, parts, 4096, 4096);
  reduce_wd<<<4096, 256, 0, stream>>>(x1, bd, parts, (float*)d_out);
}

// Round 17
// 256.625 us; speedup vs baseline: 1.0497x; 1.0497x over previous
//
#include <hip/hip_runtime.h>
#include <stdint.h>

// ---------------------------------------------------------------------------
// WindowedSelfAttentionLayer: B=2 S=2048 D=1024 H=16 HID=4096 WIN=256
//  - gemm256p: R15-MEASURED 256x256 BK=64 2-phase min-read pipeline (FROZEN;
//    5 restructure attempts failed: race / 2x-reads / spill x2 / conflicts).
//    EPI1 = QKV (Q|K + V-transposed), EPI2 = fused SwiGLU, EPI3 = Wd splitK.
//  - gemm_bf16t: m97-style 128x128 for Wo.
//  - attn_mfma: MFMA windowed attention, 80KB LDS, 2 blocks/CU.
//  - tr_cast_multi: z-fused weight transposes.  reduce_wd: 16B/lane reads.
// ---------------------------------------------------------------------------

typedef __bf16 bf16;
typedef bf16  bf16x8 __attribute__((ext_vector_type(8)));
typedef bf16  bf16x4v __attribute__((ext_vector_type(4)));
typedef float f32x4  __attribute__((ext_vector_type(4)));

#define S_LEN 2048

#define GLDS16(gp, lp)                                                          \
  __builtin_amdgcn_global_load_lds(                                            \
      (__attribute__((address_space(1))) void*)(gp),                            \
      (__attribute__((address_space(3))) void*)(lp), 16, 0, 0)

// ---------------------------------------------------------------------------
__global__ __launch_bounds__(256) void ln_bf16(const float* __restrict__ x,
                                               const float* __restrict__ w,
                                               const float* __restrict__ bb,
                                               bf16* __restrict__ out) {
  const int row = blockIdx.x, tid = threadIdx.x;
  const int wid = tid >> 6, lane = tid & 63;
  const float4 v = ((const float4*)(x + (size_t)row * 1024))[tid];
  float s = v.x + v.y + v.z + v.w;
  float q = v.x * v.x + v.y * v.y + v.z * v.z + v.w * v.w;
#pragma unroll
  for (int off = 32; off > 0; off >>= 1) {
    s += __shfl_xor(s, off);
    q += __shfl_xor(q, off);
  }
  __shared__ float rs_[4], rq_[4];
  if (lane == 0) { rs_[wid] = s; rq_[wid] = q; }
  __syncthreads();
  s = rs_[0] + rs_[1] + rs_[2] + rs_[3];
  q = rq_[0] + rq_[1] + rq_[2] + rq_[3];
  const float mean = s * (1.f / 1024.f);
  const float var  = q * (1.f / 1024.f) - mean * mean;
  const float rstd = rsqrtf(var + 1e-5f);
  const float4 wv = ((const float4*)w)[tid];
  const float4 bv = ((const float4*)bb)[tid];
  bf16x4v o;
  o[0] = (bf16)((v.x - mean) * rstd * wv.x + bv.x);
  o[1] = (bf16)((v.y - mean) * rstd * wv.y + bv.y);
  o[2] = (bf16)((v.z - mean) * rstd * wv.z + bv.z);
  o[3] = (bf16)((v.w - mean) * rstd * wv.w + bv.w);
  ((bf16x4v*)(out + (size_t)row * 1024))[tid] = o;
}

// ---------------------------------------------------------------------------
__global__ __launch_bounds__(256) void tr_cast_multi(
    const float* __restrict__ a, const float* __restrict__ b,
    const float* __restrict__ c, bf16* __restrict__ out, int R, int C) {
  const float* in = (blockIdx.z == 0) ? a : (blockIdx.z == 1 ? b : c);
  bf16* o = out + (size_t)blockIdx.z * R * C;
  __shared__ float t[32][33];
  const int tx = threadIdx.x, ty = threadIdx.y;
  const int r0 = blockIdx.y * 32, c0 = blockIdx.x * 32;
#pragma unroll
  for (int i = 0; i < 4; ++i)
    t[ty + 8 * i][tx] = in[(size_t)(r0 + ty + 8 * i) * C + c0 + tx];
  __syncthreads();
#pragma unroll
  for (int i = 0; i < 4; ++i)
    o[(size_t)(c0 + ty + 8 * i) * R + r0 + tx] = (bf16)t[tx][ty + 8 * i];
}

__global__ void concat3(const float* __restrict__ a, const float* __restrict__ b,
                        const float* __restrict__ c, float* __restrict__ o) {
  int i = blockIdx.x * 256 + threadIdx.x;
  if (i < 1024) o[i] = a[i];
  else if (i < 2048) o[i] = b[i - 1024];
  else if (i < 3072) o[i] = c[i - 2048];
}

// ---------------------------------------------------------------------------
// Min-read 256x256 GEMM pipeline (R7/R12/R15-measured).  K=1024/slice (16
// K-tiles), 512 thr = 8 waves (2Mx4N).  Per K-tile: STAGE next into other
// parity (8 gloads) -> vmcnt(8)+bar -> 24 ds_read_b128 + 64 MFMA -> bar.
// EPI1 = QKV, EPI2 = fused SwiGLU, EPI3 = Wd split-K bf16 partial.
// ---------------------------------------------------------------------------
template <int EPI>
__global__ __launch_bounds__(512, 2) void gemm256p(
    const bf16* __restrict__ A, const bf16* __restrict__ BT,
    const bf16* __restrict__ BT2, const float* __restrict__ bias,
    const float* __restrict__ bias2, bf16* __restrict__ outp,
    bf16* __restrict__ vout, bf16* __restrict__ pout,
    int Astr, int Bstr) {
  __shared__ char smem[131072];
  char* A0 = smem;
  char* A1 = smem + 32768;
  char* B0 = smem + 65536;
  char* B1 = smem + 98304;

  const int tid = threadIdx.x, wid = tid >> 6, lane = tid & 63;
  const int fr = lane & 15, fq = lane >> 4;
  const int wr = wid >> 2, wc = wid & 3;
  const int wm = wr * 128, wn = wc * 64;

  int wg = blockIdx.x;
  {
    const int nwg = gridDim.x;
    int qq = nwg >> 3, rr = nwg & 7, xc = wg & 7, ix = wg >> 3;
    wg = (xc < rr ? xc * (qq + 1) : rr * (qq + 1) + (xc - rr) * qq) + ix;
  }
  int mtile, ntile, ks = 0;
  if constexpr (EPI == 3) { mtile = wg & 15; ntile = (wg >> 4) & 3; ks = wg >> 6; }
  else                    { mtile = wg & 15; ntile = wg >> 4; }
  const int m0 = mtile * 256;
  const int nbase = (EPI == 2) ? ntile * 128 : ntile * 256;
  const size_t kbase = (size_t)ks << 10;

  const int srow = lane >> 3;
  const int segS = ((lane & 7) ^ srow) * 8;
  const size_t rsA8 = (size_t)8 * Astr;
  const size_t rsB8 = (size_t)8 * Bstr;
  const bf16* pA = A + (size_t)(m0 + wid * 32 + srow) * Astr + kbase + segS;
  const bf16* pB;
  if constexpr (EPI == 2) {
    const bf16* srcB = (wid < 4) ? BT : BT2;
    pB = srcB + (size_t)(nbase + (wid & 3) * 32 + srow) * Bstr + kbase + segS;
  } else {
    pB = BT + (size_t)(nbase + wid * 32 + srow) * Bstr + kbase + segS;
  }
  const int cOff = wid * 4096;

  auto STAGE = [&](char* aD, char* bD, int kt) {
    const size_t ko = (size_t)kt * 64;
#pragma unroll
    for (int i = 0; i < 4; ++i) {
      GLDS16(pA + i * rsA8 + ko, aD + cOff + i * 1024);
      GLDS16(pB + i * rsB8 + ko, bD + cOff + i * 1024);
    }
  };

  const int co0 = (fq * 16) ^ ((fr & 3) << 4);
  const int kh0 = (fr & 4) << 4;
  const int kh1 = 64 ^ kh0;
  const int aOff = (wm + fr) * 128 + co0;
  const int bOff = (wn + fr) * 128 + co0;

  f32x4 acc[8][4];
#pragma unroll
  for (int i = 0; i < 8; ++i)
#pragma unroll
    for (int j = 0; j < 4; ++j) acc[i][j] = f32x4{0.f, 0.f, 0.f, 0.f};

  auto COMPUTE = [&](const char* aB, const char* bB) {
#pragma unroll
    for (int kh = 0; kh < 2; ++kh) {
      const int khX = kh ? kh1 : kh0;
      bf16x8 bv[4], av[4];
#pragma unroll
      for (int nj = 0; nj < 4; ++nj)
        bv[nj] = *(const bf16x8*)(bB + bOff + nj * 2048 + khX);
#pragma unroll
      for (int q = 0; q < 4; ++q)
        av[q] = *(const bf16x8*)(aB + aOff + q * 2048 + khX);
      __builtin_amdgcn_s_setprio(1);
#pragma unroll
      for (int q = 0; q < 4; ++q)
#pragma unroll
        for (int nj = 0; nj < 4; ++nj)
          acc[q][nj] = __builtin_amdgcn_mfma_f32_16x16x32_bf16(
              av[q], bv[nj], acc[q][nj], 0, 0, 0);
      __builtin_amdgcn_s_setprio(0);
#pragma unroll
      for (int q = 0; q < 4; ++q)
        av[q] = *(const bf16x8*)(aB + aOff + 8192 + q * 2048 + khX);
      __builtin_amdgcn_s_setprio(1);
#pragma unroll
      for (int q = 0; q < 4; ++q)
#pragma unroll
        for (int nj = 0; nj < 4; ++nj)
          acc[4 + q][nj] = __builtin_amdgcn_mfma_f32_16x16x32_bf16(
              av[q], bv[nj], acc[4 + q][nj], 0, 0, 0);
      __builtin_amdgcn_s_setprio(0);
    }
  };

#define VM8()  asm volatile("s_waitcnt vmcnt(8)" ::: "memory")
#define VM0()  asm volatile("s_waitcnt vmcnt(0)" ::: "memory")
#define BAR()  __builtin_amdgcn_s_barrier()

  STAGE(A0, B0, 0);
#pragma unroll 1
  for (int t2 = 0; t2 < 7; ++t2) {
    STAGE(A1, B1, 2 * t2 + 1);  VM8();  BAR();
    COMPUTE(A0, B0);            BAR();
    STAGE(A0, B0, 2 * t2 + 2);  VM8();  BAR();
    COMPUTE(A1, B1);            BAR();
  }
  STAGE(A1, B1, 15);  VM8();  BAR();
  COMPUTE(A0, B0);    BAR();
  VM0();  BAR();
  COMPUTE(A1, B1);    BAR();

  if constexpr (EPI == 1) {
    if (nbase < 2048) {  // Q|K -> [4096][2048]
#pragma unroll
      for (int mi = 0; mi < 8; ++mi)
#pragma unroll
        for (int nj = 0; nj < 4; ++nj) {
          const int grow = m0 + wm + mi * 16 + fq * 4;
          const int gcol = nbase + wn + nj * 16 + fr;
          const float bc = bias[gcol];
#pragma unroll
          for (int r = 0; r < 4; ++r)
            outp[(size_t)(grow + r) * 2048 + gcol] = (bf16)(acc[mi][nj][r] + bc);
        }
    } else {  // V -> vT[(b*1024+d)][t]
#pragma unroll
      for (int mi = 0; mi < 8; ++mi)
#pragma unroll
        for (int nj = 0; nj < 4; ++nj) {
          const int grow = m0 + wm + mi * 16 + fq * 4;
          const int gcol = nbase + wn + nj * 16 + fr;
          const float bc = bias[gcol];
          bf16x4v pk;
#pragma unroll
          for (int r = 0; r < 4; ++r) pk[r] = (bf16)(acc[mi][nj][r] + bc);
          *(bf16x4v*)(vout + ((size_t)((grow >> 11) * 1024 + (gcol - 2048))) * 2048 +
                      (grow & 2047)) = pk;
        }
    }
  } else if constexpr (EPI == 2) {  // fused silu(g)*u
    float* uls = (float*)smem;
    if (wn >= 128) {
#pragma unroll
      for (int mi = 0; mi < 8; ++mi)
#pragma unroll
        for (int nj = 0; nj < 4; ++nj) {
          const int rowL = wm + mi * 16 + fq * 4;
          const int cu = wn - 128 + nj * 16 + fr;
          const float bc = bias2[nbase + cu];
#pragma unroll
          for (int r = 0; r < 4; ++r)
            uls[(rowL + r) * 128 + cu] = acc[mi][nj][r] + bc;
        }
    }
    __syncthreads();
    if (wn < 128) {
#pragma unroll
      for (int mi = 0; mi < 8; ++mi)
#pragma unroll
        for (int nj = 0; nj < 4; ++nj) {
          const int rowL = wm + mi * 16 + fq * 4;
          const int cg = wn + nj * 16 + fr;
          const float bc = bias[nbase + cg];
#pragma unroll
          for (int r = 0; r < 4; ++r) {
            const float g = acc[mi][nj][r] + bc;
            const float u = uls[(rowL + r) * 128 + cg];
            outp[(size_t)(m0 + rowL + r) * 4096 + nbase + cg] =
                (bf16)(g * u / (1.f + __expf(-g)));
          }
        }
    }
  } else {  // EPI 3: bf16 partial [4096][1024] for split-K slice ks
    bf16* po = pout + ((size_t)ks << 22);
#pragma unroll
    for (int mi = 0; mi < 8; ++mi)
#pragma unroll
      for (int nj = 0; nj < 4; ++nj) {
        const int grow = m0 + wm + mi * 16 + fq * 4;
        const int gcol = nbase + wn + nj * 16 + fr;
#pragma unroll
        for (int r = 0; r < 4; ++r)
          po[(size_t)(grow + r) * 1024 + gcol] = (bf16)acc[mi][nj][r];
      }
  }
#undef VM8
#undef VM0
#undef BAR
}

// out = x1 + bd + sum_{k<4} parts[k].  8 outputs/thread, 16B part reads.
__global__ __launch_bounds__(256) void reduce_wd(
    const float* __restrict__ x1, const float* __restrict__ bd,
    const bf16* __restrict__ parts, float* __restrict__ out) {
  const size_t i = ((size_t)blockIdx.x * 256 + threadIdx.x) * 2;  // float4 idx
  const float4 a0 = ((const float4*)x1)[i];
  const float4 a1 = ((const float4*)x1)[i + 1];
  const float4 bv0 = ((const float4*)bd)[i & 255];
  const float4 bv1 = ((const float4*)bd)[(i + 1) & 255];
  float s[8] = {a0.x + bv0.x, a0.y + bv0.y, a0.z + bv0.z, a0.w + bv0.w,
                a1.x + bv1.x, a1.y + bv1.y, a1.z + bv1.z, a1.w + bv1.w};
#pragma unroll
  for (int k = 0; k < 4; ++k) {
    const bf16x8 p = ((const bf16x8*)(parts + ((size_t)k << 22)))[i >> 1];
#pragma unroll
    for (int e = 0; e < 8; ++e) s[e] += (float)p[e];
  }
  ((float4*)out)[i]     = make_float4(s[0], s[1], s[2], s[3]);
  ((float4*)out)[i + 1] = make_float4(s[4], s[5], s[6], s[7]);
}

// ---------------------------------------------------------------------------
// m97-style 128x128 GEMM.  EPI 1: fp32 out + residual (Wo).
// ---------------------------------------------------------------------------
template <int EPI>
__global__ __launch_bounds__(256) void gemm_bf16t(
    const bf16* __restrict__ A, const bf16* __restrict__ BT,
    const float* __restrict__ bias, const float* __restrict__ res,
    void* __restrict__ Cout, int M, int N, int K) {
  __shared__ bf16 sA[128 * 64];
  __shared__ bf16 sB[128 * 64];
  const int tid = threadIdx.x;
  const int wid = tid >> 6, lane = tid & 63;
  const int m0 = blockIdx.y * 128, n0 = blockIdx.x * 128;
  const int wm = (wid >> 1) * 64, wn = (wid & 1) * 64;
  const int lrow = lane >> 3, lseg = (lane & 7) * 8;
  const int fr = lane & 15, fq = lane >> 4;

  f32x4 acc[4][4];
#pragma unroll
  for (int i = 0; i < 4; ++i)
#pragma unroll
    for (int j = 0; j < 4; ++j) acc[i][j] = f32x4{0.f, 0.f, 0.f, 0.f};

  for (int k0 = 0; k0 < K; k0 += 64) {
#pragma unroll
    for (int it = 0; it < 4; ++it) {
      const int c = wid * 4 + it;
      const int row = c * 8 + lrow;
      GLDS16(A  + (size_t)(m0 + row) * K + k0 + lseg, sA + c * 512);
      GLDS16(BT + (size_t)(n0 + row) * K + k0 + lseg, sB + c * 512);
    }
    __syncthreads();
#pragma unroll
    for (int kk = 0; kk < 64; kk += 32) {
      bf16x8 af[4], bfv[4];
#pragma unroll
      for (int i = 0; i < 4; ++i)
        af[i] = *(const bf16x8*)(sA + (wm + i * 16 + fr) * 64 + kk + 8 * fq);
#pragma unroll
      for (int j = 0; j < 4; ++j)
        bfv[j] = *(const bf16x8*)(sB + (wn + j * 16 + fr) * 64 + kk + 8 * fq);
#pragma unroll
      for (int i = 0; i < 4; ++i)
#pragma unroll
        for (int j = 0; j < 4; ++j)
          acc[i][j] = __builtin_amdgcn_mfma_f32_16x16x32_bf16(af[i], bfv[j],
                                                              acc[i][j], 0, 0, 0);
    }
    __syncthreads();
  }

#pragma unroll
  for (int i = 0; i < 4; ++i) {
    const int grow = m0 + wm + i * 16 + fq * 4;
#pragma unroll
    for (int j = 0; j < 4; ++j) {
      const int gcol = n0 + wn + j * 16 + fr;
      const float bc = bias[gcol];
#pragma unroll
      for (int r = 0; r < 4; ++r) {
        const size_t idx = (size_t)(grow + r) * N + gcol;
        const float v = acc[i][j][r] + bc;
        if constexpr (EPI == 1) {
          ((float*)Cout)[idx] = v + res[idx];
        } else {
          ((bf16*)Cout)[idx] = (bf16)v;
        }
      }
    }
  }
}

// ---------------------------------------------------------------------------
// MFMA windowed attention, 80KB LDS, 2 blocks/CU (R12/R15-measured).
// ---------------------------------------------------------------------------
__global__ __launch_bounds__(256) void attn_mfma(const bf16* __restrict__ qk,
                                                 const bf16* __restrict__ vT,
                                                 bf16* __restrict__ ctx) {
  __shared__ bf16 sK[320 * 64];
  __shared__ bf16 sP[64 * 320];
  const int bh = blockIdx.x;
  const int b = bh >> 4, h = bh & 15;
  const int qs0 = blockIdx.y * 64;
  const int t0 = qs0 - 128;
  const int tS = t0 < 0 ? 0 : (t0 > S_LEN - 320 ? S_LEN - 320 : t0);
  const int tid = threadIdx.x, wid = tid >> 6, lane = tid & 63;
  const size_t bbase = (size_t)b * S_LEN;

  {
    const int srow8 = lane >> 3;
    const int gseg = (lane & 7) ^ srow8;
#pragma unroll
    for (int i = 0; i < 10; ++i) {
      const int c = wid * 10 + i;
      const bf16* gp = qk + (bbase + tS + 8 * c + srow8) * 2048 + 1024 +
                       h * 64 + gseg * 8;
      GLDS16(gp, (char*)sK + c * 1024);
    }
  }
  __syncthreads();

  const int fr = lane & 15, fq = lane >> 4;
  const int fx = fr & 7;

  const bf16* qrowp = qk + (bbase + qs0 + wid * 16 + fr) * 2048 + h * 64;
  const bf16x8 aq0 = *(const bf16x8*)(qrowp + 8 * fq);
  const bf16x8 aq1 = *(const bf16x8*)(qrowp + 32 + 8 * fq);

  f32x4 s[20];
#pragma unroll
  for (int j = 0; j < 20; ++j) s[j] = f32x4{0.f, 0.f, 0.f, 0.f};
#pragma unroll
  for (int j = 0; j < 20; ++j) {
    const bf16* kb = sK + (j * 16 + fr) * 64;
    const bf16x8 bk0 = *(const bf16x8*)(kb + ((fq ^ fx) << 3));
    const bf16x8 bk1 = *(const bf16x8*)(kb + (((4 + fq) ^ fx) << 3));
    s[j] = __builtin_amdgcn_mfma_f32_16x16x32_bf16(aq0, bk0, s[j], 0, 0, 0);
    s[j] = __builtin_amdgcn_mfma_f32_16x16x32_bf16(aq1, bk1, s[j], 0, 0, 0);
  }

#pragma unroll
  for (int r = 0; r < 4; ++r) {
    const int rowq = wid * 16 + fq * 4 + r;
    const int q_g = qs0 + rowq;
    float m = -1e30f;
#pragma unroll
    for (int j = 0; j < 20; ++j) {
      const int t_g = tS + j * 16 + fr;
      const bool ok = (unsigned)(q_g - t_g + 128) <= 256u;
      const float val = ok ? s[j][r] * 0.125f : -1e30f;
      s[j][r] = val;
      m = fmaxf(m, val);
    }
#pragma unroll
    for (int off = 1; off < 16; off <<= 1) m = fmaxf(m, __shfl_xor(m, off));
    float sm = 0.f;
#pragma unroll
    for (int j = 0; j < 20; ++j) {
      const float p = __expf(s[j][r] - m);
      s[j][r] = p;
      sm += p;
    }
#pragma unroll
    for (int off = 1; off < 16; off <<= 1) sm += __shfl_xor(sm, off);
    const float inv = 1.f / sm;
    const int rk = rowq & 7;
#pragma unroll
    for (int j = 0; j < 20; ++j) {
      const int seg = 2 * j + (fr >> 3);
      sP[rowq * 320 + (((seg ^ rk) << 3) | fx)] = (bf16)(s[j][r] * inv);
    }
  }
  __syncthreads();

  f32x4 o[4];
#pragma unroll
  for (int j = 0; j < 4; ++j) o[j] = f32x4{0.f, 0.f, 0.f, 0.f};
  const bf16* vbase = vT + ((size_t)bh * 64) * 2048 + tS;
  const bf16* pbase = sP + (wid * 16 + fr) * 320;
#pragma unroll
  for (int ks = 0; ks < 10; ++ks) {
    const int kk = ks * 32;
    const bf16x8 pa = *(const bf16x8*)(pbase + (((4 * ks + fq) ^ fx) << 3));
#pragma unroll
    for (int j = 0; j < 4; ++j) {
      const bf16x8 vb = *(const bf16x8*)(vbase + (size_t)(j * 16 + fr) * 2048 +
                                         kk + 8 * fq);
      o[j] = __builtin_amdgcn_mfma_f32_16x16x32_bf16(pa, vb, o[j], 0, 0, 0);
    }
  }
#pragma unroll
  for (int j = 0; j < 4; ++j)
#pragma unroll
    for (int r = 0; r < 4; ++r) {
      const int q = qs0 + wid * 16 + fq * 4 + r;
      ctx[(bbase + q) * 1024 + h * 64 + j * 16 + fr] = (bf16)o[j][r];
    }
}

// ---------------------------------------------------------------------------
extern "C" void kernel_launch(void* const* d_in, const int* in_sizes, int n_in,
                              void* d_out, int out_size, void* d_ws, size_t ws_size,
                              hipStream_t stream) {
  const float* x    = (const float*)d_in[0];
  const float* ln1w = (const float*)d_in[2];
  const float* ln1b = (const float*)d_in[3];
  const float* Wq   = (const float*)d_in[4];
  const float* bq   = (const float*)d_in[5];
  const float* Wk   = (const float*)d_in[6];
  const float* bk   = (const float*)d_in[7];
  const float* Wv   = (const float*)d_in[8];
  const float* bv   = (const float*)d_in[9];
  const float* Wo   = (const float*)d_in[10];
  const float* bo   = (const float*)d_in[11];
  const float* ln2w = (const float*)d_in[12];
  const float* ln2b = (const float*)d_in[13];
  const float* Wg   = (const float*)d_in[14];
  const float* bg   = (const float*)d_in[15];
  const float* Wu   = (const float*)d_in[16];
  const float* bu   = (const float*)d_in[17];
  const float* Wd   = (const float*)d_in[18];
  const float* bd   = (const float*)d_in[19];

  char* ws = (char*)d_ws;
  size_t off = 0;
  auto take = [&](size_t bytes) {
    char* p = ws + off;
    off += (bytes + 255) & ~(size_t)255;
    return p;
  };
  bf16*  wqkvT = (bf16*)take((size_t)3072 * 1024 * 2);
  bf16*  woT   = (bf16*)take((size_t)1024 * 1024 * 2);
  bf16*  wgT   = (bf16*)take((size_t)4096 * 1024 * 2);
  bf16*  wuT   = (bf16*)take((size_t)4096 * 1024 * 2);
  bf16*  wdT   = (bf16*)take((size_t)1024 * 4096 * 2);
  float* bqkv  = (float*)take((size_t)3072 * 4);
  bf16*  h     = (bf16*)take((size_t)4096 * 1024 * 2);   // 8MB  } h..vT: 40MB
  bf16*  qk    = (bf16*)take((size_t)4096 * 2048 * 2);   // 16MB } dead by Wd;
  bf16*  ctx   = (bf16*)take((size_t)4096 * 1024 * 2);   // 8MB  } partials=32MB
  bf16*  vT    = (bf16*)take((size_t)2048 * 2048 * 2);   // 8MB  }
  float* x1    = (float*)take((size_t)4096 * 1024 * 4);
  bf16*  h2    = (bf16*)take((size_t)4096 * 1024 * 2);
  bf16*  gated = (bf16*)take((size_t)4096 * 4096 * 2);
  bf16*  parts = h;
  (void)ws_size; (void)in_sizes; (void)n_in; (void)out_size;

  const dim3 tb(32, 8);
  tr_cast_multi<<<dim3(32, 32, 3), tb, 0, stream>>>(Wq, Wk, Wv, wqkvT, 1024, 1024);
  tr_cast_multi<<<dim3(128, 32, 2), tb, 0, stream>>>(Wg, Wu, nullptr, wgT, 1024, 4096);
  tr_cast_multi<<<dim3(32, 128, 1), tb, 0, stream>>>(Wd, nullptr, nullptr, wdT, 4096, 1024);
  tr_cast_multi<<<dim3(32, 32, 1), tb, 0, stream>>>(Wo, nullptr, nullptr, woT, 1024, 1024);
  concat3<<<12, 256, 0, stream>>>(bq, bk, bv, bqkv);

  // LN1 -> h
  ln_bf16<<<4096, 256, 0, stream>>>(x, ln1w, ln1b, h);
  // QKV on gemm256p (grid 16m x 12n = 192): Q|K -> qk, V -> vT
  gemm256p<1><<<192, 512, 0, stream>>>(h, wqkvT, nullptr, bqkv, nullptr,
                                       qk, vT, nullptr, 1024, 1024);
  // windowed attention -> ctx bf16
  attn_mfma<<<dim3(32, 32), 256, 0, stream>>>(qk, vT, ctx);
  // x1 = x + ctx @ Wo + bo
  gemm_bf16t<1><<<dim3(8, 32), 256, 0, stream>>>(ctx, woT, bo, x,
                                                 x1, 4096, 1024, 1024);
  // LN2 -> h2
  ln_bf16<<<4096, 256, 0, stream>>>(x1, ln2w, ln2b, h2);
  // gated = silu(h2@Wg+bg) * (h2@Wu+bu)
  gemm256p<2><<<512, 512, 0, stream>>>(h2, wgT, wuT, bg, bu, gated,
                                       nullptr, nullptr, 1024, 1024);
  // Wd split-K=4: bf16 partials, then out = x1 + bd + sum(parts)
  gemm256p<3><<<256, 512, 0, stream>>>(gated, wdT, nullptr, nullptr, nullptr,
                                       nullptr, nullptr, parts, 4096, 4096);
  reduce_wd<<<2048, 256, 0, stream>>>(x1, bd, parts, (float*)d_out);
}